// Round 3
// baseline (331.572 us; speedup 1.0000x reference)
//
#include <hip/hip_runtime.h>
#include <cstdio>

// ---------------------------------------------------------------------------
// MemoryEfficientRGBDecoderStem — algebraic reduction + fused bf16 MFMA.
//   GEMM1 K collapses 1156 -> 136 (pad 144): gestalt is spatially constant
//   (per-batch Wg), cos embeddings separable in h/w.
//   R3: barrier-free main loop. Each wave owns 32 rows x all hidden x all n2.
//   GEMM1 C-layout -> GEMM2 A-layout via __shfl_xor(32) in-register transform
//   (no lS round-trip, no per-chunk __syncthreads).
// ---------------------------------------------------------------------------

#define NFREQ 16
#define BB 16
#define G 256
#define KIN 1156
#define K1 144

typedef unsigned short u16;
using bf16x8 = __bf16 __attribute__((ext_vector_type(8)));
using f32x16 = float __attribute__((ext_vector_type(16)));
using f32x4  = float __attribute__((ext_vector_type(4)));

__device__ __forceinline__ u16 f2bf(float f) {
  unsigned u = __float_as_uint(f);
  u += 0x7fffu + ((u >> 16) & 1u);
  return (u16)(u >> 16);
}
__device__ __forceinline__ unsigned pk2(float a, float b) {
  return (unsigned)f2bf(a) | ((unsigned)f2bf(b) << 16);
}
__device__ __forceinline__ float silu(float h) {
  return h / (1.f + __expf(-h));
}

// --------------------------- prologue kernels ------------------------------

// cos tables: cosx[b][f][w], cosy[b][f][h] — exact fp32 op-order of reference
__global__ void k_tables(const float* __restrict__ pos,
                         float* __restrict__ cosx, float* __restrict__ cosy) {
  int idx = blockIdx.x * 256 + threadIdx.x;   // 0..65535
  int table = idx >> 15;
  int rem = idx & 32767;
  int b = rem >> 11;
  int f = (rem >> 7) & 15;
  int c = rem & 127;
  float p0 = pos[b * 4 + 0];
  float p1 = pos[b * 4 + 1];
  float p3 = pos[b * 4 + 3];
  float x = fminf(fmaxf(p0, -1.f), 1.f);
  float y = fminf(fmaxf(p1, -1.f), 1.f);
  float stdv = 0.1f / fminf(fmaxf(p3, 0.0078125f), 0.5f);  // min_std = 1/128
  const float half_pi = 1.57079632679489661923f;
  float g = ((float)c / 127.0f) * 2.0f - 1.0f;
  float ng = (table == 0) ? ((g - x) * stdv) * half_pi      // std_x = std*(W/H)=std
                          : ((g - y) * stdv) * half_pi;
  float freq = (float)(1 << f);
  float val = cosf(ng * freq);
  if (table == 0) cosx[(b * NFREQ + f) * 128 + c] = val;
  else            cosy[(b * NFREQ + f) * 128 + c] = val;
}

// W2 (fp32 [256][1024]) -> frag-contiguous bf16 W2F:
// elem = ((kc*8 + ct)*64 + lane)*8 + i ; n2 = ct*32 + (lane&31),
// k2 = kc*16 + (lane>>5)*8 + i
__global__ void k_w2f(const float* __restrict__ w2, u16* __restrict__ W2F) {
  int e = blockIdx.x * 256 + threadIdx.x;     // 0..262143
  int i    = e & 7;
  int lane = (e >> 3) & 63;
  int ct   = (e >> 9) & 7;
  int kc   = e >> 12;
  int n2 = ct * 32 + (lane & 31);
  int k2 = kc * 16 + (lane >> 5) * 8 + i;
  W2F[e] = f2bf(w2[n2 * 1024 + k2]);
}

// B1F: per-batch reduced W1, frag-contiguous bf16.
// k layout [0,144): 64 x-emb, 64 y-emb, 4 Wg(mask), 4 Wd(depth), 8 pad.
// elem = ((((b*32 + ch)*9 + ks)*64) + lhi*32 + (n&31))*8 + i
//   hidden n = ch*32 + (n&31), k = ks*16 + lhi*8 + i
__global__ void k_b1f(const float* __restrict__ w1, const float* __restrict__ gestalt,
                      u16* __restrict__ B1F) {
  __shared__ float w1row[KIN];
  __shared__ float gest[BB * G];
  __shared__ float psum[256];
  __shared__ float wg[64];
  const int n = blockIdx.x;
  const int t = threadIdx.x;
  for (int i = t; i < KIN; i += 256) w1row[i] = w1[(size_t)n * KIN + i];
  for (int i = t; i < BB * G; i += 256) gest[i] = gestalt[i];
  __syncthreads();
  {
    // Wg[bb][j] = sum_c gestalt[bb][c] * w1[n][4c+j], split over q=4 partials
    int bb = t >> 4, j = (t >> 2) & 3, q = t & 3;
    float acc = 0.f;
#pragma unroll 8
    for (int c = q * 64; c < q * 64 + 64; ++c)
      acc += gest[bb * G + c] * w1row[4 * c + j];
    psum[t] = acc;
  }
  __syncthreads();
  if (t < 64) {
    const float* p = &psum[(t >> 2) * 16 + (t & 3) * 4];
    wg[t] = p[0] + p[1] + p[2] + p[3];
  }
  __syncthreads();
  const int ch = n >> 5, l31n = n & 31;
  for (int e = t; e < BB * K1; e += 256) {
    int bb = e / K1, k = e - bb * K1;
    float v;
    if (k < 64)       v = w1row[1024 + 8 * (k >> 2) + (k & 3)];
    else if (k < 128) { int kk = k - 64; v = w1row[1024 + 8 * (kk >> 2) + 4 + (kk & 3)]; }
    else if (k < 132) v = wg[bb * 4 + (k - 128)];
    else if (k < 136) v = w1row[1152 + (k - 132)];
    else              v = 0.f;
    int ks = k >> 4, lhi2 = (k >> 3) & 1, ii = k & 7;
    size_t idx = ((((size_t)bb * 32 + ch) * 9 + ks) * 64 + lhi2 * 32 + l31n) * 8 + ii;
    B1F[idx] = f2bf(v);
  }
}

// ------------------------------ main kernel --------------------------------
// 512 blocks x 256 thr (4 waves). Wave w owns rows [w*32, w*32+32) of the
// block's 128-row tile, ALL 1024 hidden (32 chunks), ALL 256 n2 (8 ct frags).
// Main loop has ZERO barriers: GEMM1 B-op frags register-cached from lA,
// GEMM1 C -> GEMM2 A-op via shfl_xor(32) + cndmask, af/wf are contiguous 1KB
// wave loads shared by all 4 waves (L1-served).
__global__ __launch_bounds__(256, 2) void k_main(
    const u16* __restrict__ B1F, const u16* __restrict__ W2F,
    const float* __restrict__ mask, const float* __restrict__ depth,
    const float* __restrict__ cosx, const float* __restrict__ cosy,
    const float* __restrict__ bias1, const float* __restrict__ bias2,
    float* __restrict__ out)
{
  __shared__ __align__(16) u16 lA[128 * 152];   // 38912 B
  __shared__ __align__(16) float stg[3136];     // 12544 B

  const int tid = threadIdx.x;
  const int w = tid >> 6;
  const int lane = tid & 63;
  const int l31 = lane & 31;
  const int lhi = lane >> 5;
  const int r0 = blockIdx.x * 128;
  const int b = r0 >> 12;
  const int oy0 = (r0 >> 6) & 63;   // even

  // ---- stage tables: cosx[b] (2048f), cosy[b] 4 h-rows (64f), mask/depth 4 rows ----
  {
    const float4* cx4 = (const float4*)(cosx + (size_t)b * 2048);
    ((float4*)stg)[tid]       = cx4[tid];
    ((float4*)stg)[tid + 256] = cx4[tid + 256];
    if (tid < 64)
      stg[2048 + tid] = cosy[((size_t)b * 16 + (tid >> 2)) * 128 + 2 * oy0 + (tid & 3)];
    if (tid < 128) {
      ((float4*)(stg + 2112))[tid] = ((const float4*)(mask  + ((size_t)b * 128 + 2 * oy0) * 128))[tid];
      ((float4*)(stg + 2624))[tid] = ((const float4*)(depth + ((size_t)b * 128 + 2 * oy0) * 128))[tid];
    }
  }
  __syncthreads();

  // ---- build lA[row][k] (u16 stride 152) ----
  {
    const int rl = tid & 127;      // row in tile
    const int kh = tid >> 7;       // wave-uniform k-half
    const int oyl = rl >> 6, ox = rl & 63;
    float m[4], dd[4];
#pragma unroll
    for (int j = 0; j < 4; ++j) {
      int sy = j >> 1, sx = j & 1;
      float mv = stg[2112 + (2 * oyl + sy) * 128 + 2 * ox + sx];
      m[j] = mv;
      dd[j] = stg[2624 + (2 * oyl + sy) * 128 + 2 * ox + sx] * mv;
    }
    unsigned* dst = (unsigned*)(lA + rl * 152);
    if (kh == 0) {
#pragma unroll
      for (int kk = 0; kk < 18; ++kk) {
        const int k0 = kk * 4;
        float v0, v1, v2, v3;
        if (k0 < 64) {          // x-emb
          const int f = k0 >> 2;
          float ca = stg[f * 128 + 2 * ox], cb = stg[f * 128 + 2 * ox + 1];
          v0 = m[0] * ca; v1 = m[1] * cb; v2 = m[2] * ca; v3 = m[3] * cb;
        } else {                // y-emb f=0,1
          const int f = (k0 - 64) >> 2;
          float ca = stg[2048 + f * 4 + 2 * oyl], cb = stg[2048 + f * 4 + 2 * oyl + 1];
          v0 = m[0] * ca; v1 = m[1] * ca; v2 = m[2] * cb; v3 = m[3] * cb;
        }
        dst[k0 / 2]     = pk2(v0, v1);
        dst[k0 / 2 + 1] = pk2(v2, v3);
      }
    } else {
#pragma unroll
      for (int kk = 0; kk < 18; ++kk) {
        const int k0 = 72 + kk * 4;
        float v0, v1, v2, v3;
        if (k0 < 128) {         // y-emb f=2..15
          const int f = (k0 - 64) >> 2;
          float ca = stg[2048 + f * 4 + 2 * oyl], cb = stg[2048 + f * 4 + 2 * oyl + 1];
          v0 = m[0] * ca; v1 = m[1] * ca; v2 = m[2] * cb; v3 = m[3] * cb;
        } else if (k0 == 128) { v0 = m[0]; v1 = m[1]; v2 = m[2]; v3 = m[3]; }
        else if (k0 == 132)   { v0 = dd[0]; v1 = dd[1]; v2 = dd[2]; v3 = dd[3]; }
        else                  { v0 = v1 = v2 = v3 = 0.f; }
        dst[k0 / 2]     = pk2(v0, v1);
        dst[k0 / 2 + 1] = pk2(v2, v3);
      }
    }
  }
  __syncthreads();

  // ---- register-cache this wave's 32-row B-op frags (rows w*32 .. +32) ----
  bf16x8 bfr[9];
  const int rowbase = (w * 32 + l31) * 152 + lhi * 8;
#pragma unroll
  for (int ks = 0; ks < 9; ++ks) bfr[ks] = *(const bf16x8*)&lA[rowbase + ks * 16];

  f32x16 acc2[8];
#pragma unroll
  for (int c = 0; c < 8; ++c)
#pragma unroll
    for (int i = 0; i < 16; ++i) acc2[c][i] = 0.f;

  const u16* b1p = B1F + (size_t)b * 32 * 4608 + (size_t)lane * 8;
  const u16* w2p = W2F + (size_t)lane * 8;

  for (int ch = 0; ch < 32; ++ch) {
    // GEMM1: C[hidden 32][row 32] for this wave's rows
    f32x16 acc1;
#pragma unroll
    for (int i = 0; i < 16; ++i) acc1[i] = 0.f;
    const u16* ap = b1p + (size_t)ch * 4608;
#pragma unroll
    for (int ks = 0; ks < 9; ++ks) {
      bf16x8 af = *(const bf16x8*)(ap + ks * 512);   // 1KB contiguous wave load
      acc1 = __builtin_amdgcn_mfma_f32_32x32x16_bf16(af, bfr[ks], acc1, 0, 0, 0);
    }

    // bias + SiLU + pack to bf16 pairs (C rows ascending per reg group)
    const int n0 = ch * 32;
    unsigned d[8];
#pragma unroll
    for (int q = 0; q < 4; ++q) {
      f32x4 bs = *(const f32x4*)(bias1 + n0 + 8 * q + 4 * lhi);
      float h0 = acc1[4 * q + 0] + bs[0];
      float h1 = acc1[4 * q + 1] + bs[1];
      float h2 = acc1[4 * q + 2] + bs[2];
      float h3 = acc1[4 * q + 3] + bs[3];
      d[2 * q]     = pk2(silu(h0), silu(h1));
      d[2 * q + 1] = pk2(silu(h2), silu(h3));
    }
    // C-layout -> A-op layout: exchange with lane^32, then half-select.
    unsigned y0 = (unsigned)__shfl_xor((int)(lhi ? d[0] : d[2]), 32);
    unsigned y1 = (unsigned)__shfl_xor((int)(lhi ? d[1] : d[3]), 32);
    unsigned y2 = (unsigned)__shfl_xor((int)(lhi ? d[4] : d[6]), 32);
    unsigned y3 = (unsigned)__shfl_xor((int)(lhi ? d[5] : d[7]), 32);
    uint4 fa, fb;
    fa.x = lhi ? y0 : d[0];  fa.y = lhi ? y1 : d[1];
    fa.z = lhi ? d[2] : y0;  fa.w = lhi ? d[3] : y1;
    fb.x = lhi ? y2 : d[4];  fb.y = lhi ? y3 : d[5];
    fb.z = lhi ? d[6] : y2;  fb.w = lhi ? d[7] : y3;
    bf16x8 fragA = __builtin_bit_cast(bf16x8, fa);   // k = ch*32 + 0..15
    bf16x8 fragB = __builtin_bit_cast(bf16x8, fb);   // k = ch*32 + 16..31

    // GEMM2: acc2[ct] += S[rows][k16] * W2[n2][k16], two k-chunks
    const u16* wpa = w2p + (size_t)(2 * ch) * 4096;
#pragma unroll
    for (int ct = 0; ct < 8; ++ct) {
      bf16x8 wf = *(const bf16x8*)(wpa + ct * 512);
      acc2[ct] = __builtin_amdgcn_mfma_f32_32x32x16_bf16(fragA, wf, acc2[ct], 0, 0, 0);
    }
#pragma unroll
    for (int ct = 0; ct < 8; ++ct) {
      bf16x8 wf = *(const bf16x8*)(wpa + 4096 + ct * 512);
      acc2[ct] = __builtin_amdgcn_mfma_f32_32x32x16_bf16(fragB, wf, acc2[ct], 0, 0, 0);
    }
  }

  // ---- epilogue: out[b][n2][oy][ox] = acc2 + bias2, float4 along ox ----
#pragma unroll
  for (int ct = 0; ct < 8; ++ct) {
    const int n2 = ct * 32 + l31;
    const float b2 = bias2[n2];
    float* ob = out + ((size_t)b * 256 + n2) * 4096;
#pragma unroll
    for (int q = 0; q < 4; ++q) {
      const int rl = w * 32 + 8 * q + 4 * lhi;   // rows rl..rl+3 consecutive
      const int oy = oy0 + (rl >> 6);
      const int ox = rl & 63;
      f32x4 v;
      v[0] = acc2[ct][4 * q + 0] + b2;
      v[1] = acc2[ct][4 * q + 1] + b2;
      v[2] = acc2[ct][4 * q + 2] + b2;
      v[3] = acc2[ct][4 * q + 3] + b2;
      *(f32x4*)(ob + oy * 64 + ox) = v;
    }
  }
}

// ------------------------------- launcher ----------------------------------

extern "C" void kernel_launch(void* const* d_in, const int* in_sizes, int n_in,
                              void* d_out, int out_size, void* d_ws, size_t ws_size,
                              hipStream_t stream) {
  const float* pos     = (const float*)d_in[0];
  const float* gestalt = (const float*)d_in[1];
  const float* mask    = (const float*)d_in[2];
  const float* depth   = (const float*)d_in[3];
  const float* w1      = (const float*)d_in[4];
  const float* bias1   = (const float*)d_in[5];
  const float* w2      = (const float*)d_in[6];
  const float* bias2   = (const float*)d_in[7];
  float* out = (float*)d_out;

  // workspace: cosx 128KB | cosy 128KB | B1F 4.5MB | W2F 512KB = 5,505,024 B
  const size_t NEED = 131072u + 131072u + 4718592u + 524288u;
  if (ws_size < NEED) {
    fprintf(stderr, "[kernel] ws_size=%zu < needed %zu — skipping launches\n",
            ws_size, NEED);
    return;
  }
  char* ws = (char*)d_ws;
  float* cosx = (float*)(ws);
  float* cosy = (float*)(ws + 131072);
  u16*   B1F  = (u16*)(ws + 262144);
  u16*   W2F  = (u16*)(ws + 262144 + 4718592);

  k_tables<<<256, 256, 0, stream>>>(pos, cosx, cosy);
  k_w2f<<<1024, 256, 0, stream>>>(w2, W2F);
  k_b1f<<<1024, 256, 0, stream>>>(w1, gestalt, B1F);
  k_main<<<512, 256, 0, stream>>>(B1F, W2F, mask, depth, cosx, cosy, bias1, bias2, out);
}

// Round 4
// 185.045 us; speedup vs baseline: 1.7918x; 1.7918x over previous
//
#include <hip/hip_runtime.h>
#include <cstdio>

// ---------------------------------------------------------------------------
// MemoryEfficientRGBDecoderStem — algebraic reduction + fused bf16 MFMA.
//   GEMM1 K collapses 1156 -> 136 (pad 144): gestalt spatially constant
//   (per-batch Wg), cos embeddings separable in h/w.
//   R4: 3-stage async LDS pipeline (global_load_lds width=16) feeds all 4
//   waves' MFMA operands; B-op frags built directly in registers; barrier-free
//   GEMM1->GEMM2 handoff via shfl_xor(32) (validated R3).
// ---------------------------------------------------------------------------

#define NFREQ 16
#define BB 16
#define G 256
#define KIN 1156
#define K1 144
#define STAGE_U16 12800   // 25600 B per stage: af 9216 B + wf 16384 B

typedef unsigned short u16;
using bf16x8 = __bf16 __attribute__((ext_vector_type(8)));
using f32x16 = float __attribute__((ext_vector_type(16)));
using f32x4  = float __attribute__((ext_vector_type(4)));

__device__ __forceinline__ u16 f2bf(float f) {
  unsigned u = __float_as_uint(f);
  u += 0x7fffu + ((u >> 16) & 1u);
  return (u16)(u >> 16);
}
__device__ __forceinline__ unsigned pk2(float a, float b) {
  return (unsigned)f2bf(a) | ((unsigned)f2bf(b) << 16);
}
__device__ __forceinline__ float silu(float h) {
  return h / (1.f + __expf(-h));
}
// async global->LDS DMA: per-lane g addr, wave-uniform LDS base; lane i -> l + 16*i
__device__ __forceinline__ void gl_lds16(const u16* g, u16* l) {
  __builtin_amdgcn_global_load_lds(
      (const __attribute__((address_space(1))) void*)g,
      (__attribute__((address_space(3))) void*)l, 16, 0, 0);
}

// --------------------------- fused prologue --------------------------------
// blocks [0,1024): B1F build | [1024,2048): W2F pack | [2048,2304): cos tables
__global__ void k_pre(const float* __restrict__ pos,
                      const float* __restrict__ gestalt,
                      const float* __restrict__ w1,
                      const float* __restrict__ w2,
                      float* __restrict__ cosx, float* __restrict__ cosy,
                      u16* __restrict__ B1F, u16* __restrict__ W2F) {
  const int bid = blockIdx.x;
  const int t = threadIdx.x;

  if (bid < 1024) {
    // ---- B1F: per-batch reduced W1, frag-contiguous bf16 ----
    __shared__ float w1row[KIN];
    __shared__ float gestT[G * BB];   // transposed [c][bb] (bank-conflict-free)
    __shared__ float psum[256];
    __shared__ float wg[64];
    const int n = bid;
    for (int i = t; i < KIN; i += 256) w1row[i] = w1[(size_t)n * KIN + i];
    for (int i = t; i < BB * G; i += 256) {
      int bb = i >> 8, c = i & 255;
      gestT[c * BB + bb] = gestalt[i];
    }
    __syncthreads();
    {
      // Wg[bb][j] = sum_c gestalt[bb][c]*w1[n][4c+j]; t = q*64 + j*16 + bb
      int bb = t & 15, j = (t >> 4) & 3, q = t >> 6;
      float acc = 0.f;
#pragma unroll 8
      for (int c = q * 64; c < q * 64 + 64; ++c)
        acc += gestT[c * BB + bb] * w1row[4 * c + j];
      psum[t] = acc;
    }
    __syncthreads();
    if (t < 64) {
      int bb = t >> 2, j = t & 3;
      wg[t] = psum[j * 16 + bb] + psum[64 + j * 16 + bb] +
              psum[128 + j * 16 + bb] + psum[192 + j * 16 + bb];
    }
    __syncthreads();
    const int ch = n >> 5, l31n = n & 31;
    for (int e = t; e < BB * K1; e += 256) {
      int bb = e / K1, k = e - bb * K1;
      float v;
      if (k < 64)       v = w1row[1024 + 8 * (k >> 2) + (k & 3)];
      else if (k < 128) { int kk = k - 64; v = w1row[1024 + 8 * (kk >> 2) + 4 + (kk & 3)]; }
      else if (k < 132) v = wg[bb * 4 + (k - 128)];
      else if (k < 136) v = w1row[1152 + (k - 132)];
      else              v = 0.f;
      int ks = k >> 4, lhi2 = (k >> 3) & 1, ii = k & 7;
      size_t idx = ((((size_t)bb * 32 + ch) * 9 + ks) * 64 + lhi2 * 32 + l31n) * 8 + ii;
      B1F[idx] = f2bf(v);
    }
  } else if (bid < 2048) {
    // ---- W2F: frag-contiguous bf16; elem=((kc*8+ct)*64+lane)*8+i ----
    int e = (bid - 1024) * 256 + t;
    int i    = e & 7;
    int lane = (e >> 3) & 63;
    int ct   = (e >> 9) & 7;
    int kc   = e >> 12;
    int n2 = ct * 32 + (lane & 31);
    int k2 = kc * 16 + (lane >> 5) * 8 + i;
    W2F[e] = f2bf(w2[n2 * 1024 + k2]);
  } else {
    // ---- cos tables (exact fp32 op-order of reference) ----
    int idx = (bid - 2048) * 256 + t;   // 0..65535
    int table = idx >> 15;
    int rem = idx & 32767;
    int b = rem >> 11;
    int f = (rem >> 7) & 15;
    int c = rem & 127;
    float p0 = pos[b * 4 + 0];
    float p1 = pos[b * 4 + 1];
    float p3 = pos[b * 4 + 3];
    float x = fminf(fmaxf(p0, -1.f), 1.f);
    float y = fminf(fmaxf(p1, -1.f), 1.f);
    float stdv = 0.1f / fminf(fmaxf(p3, 0.0078125f), 0.5f);  // min_std = 1/128
    const float half_pi = 1.57079632679489661923f;
    float g = ((float)c / 127.0f) * 2.0f - 1.0f;
    float ng = (table == 0) ? ((g - x) * stdv) * half_pi     // std_x = std (W/H=1)
                            : ((g - y) * stdv) * half_pi;
    float freq = (float)(1 << f);
    float val = cosf(ng * freq);
    if (table == 0) cosx[(b * NFREQ + f) * 128 + c] = val;
    else            cosy[(b * NFREQ + f) * 128 + c] = val;
  }
}

// ------------------------------ main kernel --------------------------------
// 512 blocks x 256 thr (4 waves). Wave w owns rows [w*32,w*32+32), all 1024
// hidden, all 256 n2. Operand streams (B1F af, W2F wf) flow through a 3-stage
// LDS pipeline filled by async global_load_lds (all 4 waves co-produce).
// One __syncthreads per ch: drains the ch+2 prefetch issued one full compute
// phase earlier (latency covered), and publishes stage buffers.
__global__ __launch_bounds__(256, 2) void k_main(
    const u16* __restrict__ B1F, const u16* __restrict__ W2F,
    const float* __restrict__ mask, const float* __restrict__ depth,
    const float* __restrict__ cosx, const float* __restrict__ cosy,
    const float* __restrict__ bias1, const float* __restrict__ bias2,
    float* __restrict__ out)
{
  __shared__ __align__(16) u16 sbuf[3 * STAGE_U16];   // 76800 B
  float* stg = (float*)sbuf;                          // staging overlay (12544 B)

  const int tid = threadIdx.x;
  const int w = tid >> 6;
  const int lane = tid & 63;
  const int l31 = lane & 31;
  const int lhi = lane >> 5;
  const int r0 = blockIdx.x * 128;
  const int b = r0 >> 12;
  const int oy0 = (r0 >> 6) & 63;   // even

  // ---- stage tables: cosx[b] 2048f | cosy[b] 4 h-rows 64f | mask,depth 4 rows ----
  {
    const float4* cx4 = (const float4*)(cosx + (size_t)b * 2048);
    ((float4*)stg)[tid]       = cx4[tid];
    ((float4*)stg)[tid + 256] = cx4[tid + 256];
    if (tid < 64)
      stg[2048 + tid] = cosy[((size_t)b * 16 + (tid >> 2)) * 128 + 2 * oy0 + (tid & 3)];
    if (tid < 128) {
      ((float4*)(stg + 2112))[tid] = ((const float4*)(mask  + ((size_t)b * 128 + 2 * oy0) * 128))[tid];
      ((float4*)(stg + 2624))[tid] = ((const float4*)(depth + ((size_t)b * 128 + 2 * oy0) * 128))[tid];
    }
  }
  __syncthreads();

  // ---- build this lane's 9 GEMM1 B-op frags directly in registers ----
  // row r = w*32+l31; k = ks*16 + lhi*8 + i
  bf16x8 bfr[9];
  {
    const int r = w * 32 + l31;
    const int oyl = r >> 6, ox = r & 63;
    float m[4], dd[4];
#pragma unroll
    for (int j = 0; j < 4; ++j) {
      int sy = j >> 1, sx = j & 1;
      float mv = stg[2112 + (2 * oyl + sy) * 128 + 2 * ox + sx];
      m[j] = mv;
      dd[j] = stg[2624 + (2 * oyl + sy) * 128 + 2 * ox + sx] * mv;
    }
#pragma unroll
    for (int ks = 0; ks < 9; ++ks) {
      const int k0 = ks * 16 + lhi * 8;
      unsigned dwords[4];
#pragma unroll
      for (int h = 0; h < 4; ++h) {
        float v[2];
#pragma unroll
        for (int p = 0; p < 2; ++p) {
          const int k = k0 + 2 * h + p;
          float vv;
          if (k < 64) {
            const int f = k >> 2, j = k & 3;
            vv = m[j] * stg[f * 128 + 2 * ox + (j & 1)];
          } else if (k < 128) {
            const int kk = k - 64, f = kk >> 2, j = kk & 3;
            vv = m[j] * stg[2048 + f * 4 + 2 * oyl + (j >> 1)];
          } else if (k < 132) {
            vv = m[k - 128];
          } else if (k < 136) {
            vv = dd[k - 132];
          } else {
            vv = 0.f;
          }
          v[p] = vv;
        }
        dwords[h] = pk2(v[0], v[1]);
      }
      uint4 u; u.x = dwords[0]; u.y = dwords[1]; u.z = dwords[2]; u.w = dwords[3];
      bfr[ks] = __builtin_bit_cast(bf16x8, u);
    }
  }
  __syncthreads();   // all stg reads done before DMA overwrites sbuf

  f32x16 acc2[8];
#pragma unroll
  for (int c = 0; c < 8; ++c)
#pragma unroll
    for (int i = 0; i < 16; ++i) acc2[c][i] = 0.f;

  const u16* b1base = B1F + (size_t)b * 32 * 4608;   // per-ch 4608 u16 (9216 B)
  const u16* w2base = W2F;                           // per-ch 8192 u16 (16384 B)

  // prefetch: 25 chunks of 1KB per ch (9 af + 16 wf), round-robin over waves
  auto prefetch = [&](int ch, int st) {
    const u16* asrc = b1base + (size_t)ch * 4608 + lane * 8;
    const u16* wsrc = w2base + (size_t)ch * 8192 + lane * 8;
    u16* dst = sbuf + st * STAGE_U16;
    for (int c = w; c < 25; c += 4) {
      if (c < 9) gl_lds16(asrc + c * 512, dst + c * 512);
      else       gl_lds16(wsrc + (c - 9) * 512, dst + 4608 + (c - 9) * 512);
    }
  };

  prefetch(0, 0);
  prefetch(1, 1);
  __syncthreads();   // vmcnt(0): stages 0,1 resident

  for (int ch = 0; ch < 32; ++ch) {
    const int st = ch % 3;
    if (ch + 2 < 32) prefetch(ch + 2, (ch + 2) % 3);   // issue early, land later

    const u16* afb = sbuf + st * STAGE_U16;
    const u16* wfb = afb + 4608;

    // GEMM1: C[hidden 32][rows 32]
    f32x16 acc1;
#pragma unroll
    for (int i = 0; i < 16; ++i) acc1[i] = 0.f;
#pragma unroll
    for (int ks = 0; ks < 9; ++ks) {
      bf16x8 af = *(const bf16x8*)(afb + ks * 512 + lane * 8);   // ds_read_b128
      acc1 = __builtin_amdgcn_mfma_f32_32x32x16_bf16(af, bfr[ks], acc1, 0, 0, 0);
    }

    // bias + SiLU + pack bf16
    const int n0 = ch * 32;
    unsigned d[8];
#pragma unroll
    for (int q = 0; q < 4; ++q) {
      f32x4 bs = *(const f32x4*)(bias1 + n0 + 8 * q + 4 * lhi);
      float h0 = acc1[4 * q + 0] + bs[0];
      float h1 = acc1[4 * q + 1] + bs[1];
      float h2 = acc1[4 * q + 2] + bs[2];
      float h3 = acc1[4 * q + 3] + bs[3];
      d[2 * q]     = pk2(silu(h0), silu(h1));
      d[2 * q + 1] = pk2(silu(h2), silu(h3));
    }
    // C-layout -> A-op layout: exchange with lane^32 + half-select (validated R3)
    unsigned y0 = (unsigned)__shfl_xor((int)(lhi ? d[0] : d[2]), 32);
    unsigned y1 = (unsigned)__shfl_xor((int)(lhi ? d[1] : d[3]), 32);
    unsigned y2 = (unsigned)__shfl_xor((int)(lhi ? d[4] : d[6]), 32);
    unsigned y3 = (unsigned)__shfl_xor((int)(lhi ? d[5] : d[7]), 32);
    uint4 fa, fb;
    fa.x = lhi ? y0 : d[0];  fa.y = lhi ? y1 : d[1];
    fa.z = lhi ? d[2] : y0;  fa.w = lhi ? d[3] : y1;
    fb.x = lhi ? y2 : d[4];  fb.y = lhi ? y3 : d[5];
    fb.z = lhi ? d[6] : y2;  fb.w = lhi ? d[7] : y3;
    bf16x8 fragA = __builtin_bit_cast(bf16x8, fa);   // k = ch*32 + 0..15
    bf16x8 fragB = __builtin_bit_cast(bf16x8, fb);   // k = ch*32 + 16..31

    // GEMM2: acc2[ct] += S[rows][k16] * W2[n2][k16]
#pragma unroll
    for (int ct = 0; ct < 8; ++ct) {
      bf16x8 wf = *(const bf16x8*)(wfb + ct * 512 + lane * 8);
      acc2[ct] = __builtin_amdgcn_mfma_f32_32x32x16_bf16(fragA, wf, acc2[ct], 0, 0, 0);
    }
#pragma unroll
    for (int ct = 0; ct < 8; ++ct) {
      bf16x8 wf = *(const bf16x8*)(wfb + 4096 + ct * 512 + lane * 8);
      acc2[ct] = __builtin_amdgcn_mfma_f32_32x32x16_bf16(fragB, wf, acc2[ct], 0, 0, 0);
    }

    __syncthreads();   // drains ch+2 DMA (issued ~1 compute-phase ago) + publishes
  }

  // ---- epilogue: out[b][n2][oy][ox] = acc2 + bias2, float4 along ox ----
#pragma unroll
  for (int ct = 0; ct < 8; ++ct) {
    const int n2 = ct * 32 + l31;
    const float b2 = bias2[n2];
    float* ob = out + ((size_t)b * 256 + n2) * 4096;
#pragma unroll
    for (int q = 0; q < 4; ++q) {
      const int rl = w * 32 + 8 * q + 4 * lhi;   // rows rl..rl+3 consecutive
      const int oy = oy0 + (rl >> 6);
      const int ox = rl & 63;
      f32x4 v;
      v[0] = acc2[ct][4 * q + 0] + b2;
      v[1] = acc2[ct][4 * q + 1] + b2;
      v[2] = acc2[ct][4 * q + 2] + b2;
      v[3] = acc2[ct][4 * q + 3] + b2;
      *(f32x4*)(ob + oy * 64 + ox) = v;
    }
  }
}

// ------------------------------- launcher ----------------------------------

extern "C" void kernel_launch(void* const* d_in, const int* in_sizes, int n_in,
                              void* d_out, int out_size, void* d_ws, size_t ws_size,
                              hipStream_t stream) {
  const float* pos     = (const float*)d_in[0];
  const float* gestalt = (const float*)d_in[1];
  const float* mask    = (const float*)d_in[2];
  const float* depth   = (const float*)d_in[3];
  const float* w1      = (const float*)d_in[4];
  const float* bias1   = (const float*)d_in[5];
  const float* w2      = (const float*)d_in[6];
  const float* bias2   = (const float*)d_in[7];
  float* out = (float*)d_out;

  // workspace: cosx 128KB | cosy 128KB | B1F 4.5MB | W2F 512KB = 5,505,024 B
  const size_t NEED = 131072u + 131072u + 4718592u + 524288u;
  if (ws_size < NEED) {
    fprintf(stderr, "[kernel] ws_size=%zu < needed %zu — skipping launches\n",
            ws_size, NEED);
    return;
  }
  char* ws = (char*)d_ws;
  float* cosx = (float*)(ws);
  float* cosy = (float*)(ws + 131072);
  u16*   B1F  = (u16*)(ws + 262144);
  u16*   W2F  = (u16*)(ws + 262144 + 4718592);

  k_pre<<<2304, 256, 0, stream>>>(pos, gestalt, w1, w2, cosx, cosy, B1F, W2F);
  k_main<<<512, 256, 0, stream>>>(B1F, W2F, mask, depth, cosx, cosy, bias1, bias2, out);
}

// Round 5
// 165.329 us; speedup vs baseline: 2.0055x; 1.1193x over previous
//
#include <hip/hip_runtime.h>
#include <cstdio>

// ---------------------------------------------------------------------------
// MemoryEfficientRGBDecoderStem — algebraic reduction + fused bf16 MFMA.
//   GEMM1 K collapses 1156 -> 136 (pad 144): gestalt spatially constant
//   (per-batch Wg), cos embeddings separable in h/w.
//   R5: VALU diet (fast silu: v_exp+v_rcp; pack via v_perm; acc1 init = bias
//   from LDS — no global loads inside loop so DMAs own vmcnt), static-unrolled
//   per-wave prefetch chunks, vectorized k_pre stores.
// ---------------------------------------------------------------------------

#define NFREQ 16
#define BB 16
#define G 256
#define KIN 1156
#define K1 144
#define STAGE_U16 12800   // 25600 B per stage: af 9216 B + wf 16384 B

typedef unsigned short u16;
using bf16x8 = __bf16 __attribute__((ext_vector_type(8)));
using f32x16 = float __attribute__((ext_vector_type(16)));
using f32x4  = float __attribute__((ext_vector_type(4)));

__device__ __forceinline__ u16 f2bf(float f) {          // RNE (for weights)
  unsigned u = __float_as_uint(f);
  u += 0x7fffu + ((u >> 16) & 1u);
  return (u16)(u >> 16);
}
__device__ __forceinline__ unsigned pk2(float a, float b) {  // RNE pair
  return (unsigned)f2bf(a) | ((unsigned)f2bf(b) << 16);
}
// fast pair pack, round-half-up: 2x v_add + v_perm_b32
__device__ __forceinline__ unsigned pk2f(float a, float b) {
  unsigned ua = __float_as_uint(a) + 0x8000u;
  unsigned ub = __float_as_uint(b) + 0x8000u;
  return __builtin_amdgcn_perm(ub, ua, 0x07060302u);  // {ub.hi16, ua.hi16}
}
// fast silu: v_mul + v_exp_f32 + v_add + v_rcp_f32 + v_mul (no fp32 div seq)
__device__ __forceinline__ float silu(float h) {
  float e = __builtin_amdgcn_exp2f(h * -1.44269504088896f);
  return h * __builtin_amdgcn_rcpf(1.f + e);
}
// async global->LDS DMA: per-lane g addr, wave-uniform LDS base; lane i -> l + 16*i
__device__ __forceinline__ void gl_lds16(const u16* g, u16* l) {
  __builtin_amdgcn_global_load_lds(
      (const __attribute__((address_space(1))) void*)g,
      (__attribute__((address_space(3))) void*)l, 16, 0, 0);
}

// --------------------------- fused prologue --------------------------------
// blocks [0,1024): B1F build | [1024,1152): W2F pack | [1152,1408): cos tables
__global__ void k_pre(const float* __restrict__ pos,
                      const float* __restrict__ gestalt,
                      const float* __restrict__ w1,
                      const float* __restrict__ w2,
                      float* __restrict__ cosx, float* __restrict__ cosy,
                      u16* __restrict__ B1F, u16* __restrict__ W2F) {
  const int bid = blockIdx.x;
  const int t = threadIdx.x;

  if (bid < 1024) {
    // ---- B1F: per-batch reduced W1, frag-contiguous bf16, uint4 stores ----
    __shared__ float w1row[KIN];
    __shared__ float gestT[G * BB];   // transposed [c][bb]
    __shared__ float psum[256];
    __shared__ float wg[64];
    const int n = bid;
    for (int i = t; i < KIN; i += 256) w1row[i] = w1[(size_t)n * KIN + i];
    for (int i = t; i < BB * G; i += 256) {
      int bb = i >> 8, c = i & 255;
      gestT[c * BB + bb] = gestalt[i];
    }
    __syncthreads();
    {
      // Wg[bb][j] = sum_c gestalt[bb][c]*w1[n][4c+j]; t = q*64 + j*16 + bb
      int bb = t & 15, j = (t >> 4) & 3, q = t >> 6;
      float acc = 0.f;
#pragma unroll 8
      for (int c = q * 64; c < q * 64 + 64; ++c)
        acc += gestT[c * BB + bb] * w1row[4 * c + j];
      psum[t] = acc;
    }
    __syncthreads();
    if (t < 64) {
      int bb = t >> 2, j = t & 3;
      wg[t] = psum[j * 16 + bb] + psum[64 + j * 16 + bb] +
              psum[128 + j * 16 + bb] + psum[192 + j * 16 + bb];
    }
    __syncthreads();
    const int ch = n >> 5, l31n = n & 31;
    // 288 chunks of 8 consecutive k; one uint4 store each
    for (int c = t; c < BB * (K1 / 8); c += 256) {
      int bb = c / 18, kc = c - bb * 18;
      int k0 = kc * 8;
      float v[8];
#pragma unroll
      for (int i = 0; i < 8; ++i) {
        int k = k0 + i;
        float vv;
        if (k < 64)       vv = w1row[1024 + 8 * (k >> 2) + (k & 3)];
        else if (k < 128) { int kk = k - 64; vv = w1row[1024 + 8 * (kk >> 2) + 4 + (kk & 3)]; }
        else if (k < 132) vv = wg[bb * 4 + (k - 128)];
        else if (k < 136) vv = w1row[1152 + (k - 132)];
        else              vv = 0.f;
        v[i] = vv;
      }
      uint4 u;
      u.x = pk2(v[0], v[1]); u.y = pk2(v[2], v[3]);
      u.z = pk2(v[4], v[5]); u.w = pk2(v[6], v[7]);
      size_t idx0 = ((((size_t)bb * 32 + ch) * 9 + (kc >> 1)) * 64 +
                     (kc & 1) * 32 + l31n) * 8;
      *(uint4*)(B1F + idx0) = u;
    }
  } else if (bid < 1152) {
    // ---- W2F: frag-contiguous bf16; 8 u16 per thread, uint4 store ----
    int e8 = (bid - 1024) * 256 + t;    // 0..32767
    int lane = e8 & 63;
    int ct   = (e8 >> 6) & 7;
    int kc   = e8 >> 9;
    int n2 = ct * 32 + (lane & 31);
    int k2 = kc * 16 + (lane >> 5) * 8;
    const float* src = w2 + (size_t)n2 * 1024 + k2;
    uint4 u;
    u.x = pk2(src[0], src[1]); u.y = pk2(src[2], src[3]);
    u.z = pk2(src[4], src[5]); u.w = pk2(src[6], src[7]);
    *(uint4*)(W2F + (size_t)e8 * 8) = u;
  } else {
    // ---- cos tables (exact fp32 op-order of reference) ----
    int idx = (bid - 1152) * 256 + t;   // 0..65535
    int table = idx >> 15;
    int rem = idx & 32767;
    int b = rem >> 11;
    int f = (rem >> 7) & 15;
    int c = rem & 127;
    float p0 = pos[b * 4 + 0];
    float p1 = pos[b * 4 + 1];
    float p3 = pos[b * 4 + 3];
    float x = fminf(fmaxf(p0, -1.f), 1.f);
    float y = fminf(fmaxf(p1, -1.f), 1.f);
    float stdv = 0.1f / fminf(fmaxf(p3, 0.0078125f), 0.5f);  // min_std = 1/128
    const float half_pi = 1.57079632679489661923f;
    float g = ((float)c / 127.0f) * 2.0f - 1.0f;
    float ng = (table == 0) ? ((g - x) * stdv) * half_pi     // std_x = std (W/H=1)
                            : ((g - y) * stdv) * half_pi;
    float freq = (float)(1 << f);
    float val = cosf(ng * freq);
    if (table == 0) cosx[(b * NFREQ + f) * 128 + c] = val;
    else            cosy[(b * NFREQ + f) * 128 + c] = val;
  }
}

// ------------------------------ main kernel --------------------------------
// 512 blocks x 256 thr (4 waves). Wave w owns rows [w*32,w*32+32), all 1024
// hidden, all 256 n2. Operand streams (af, wf) flow through a 3-stage LDS
// pipeline filled by async global_load_lds; wave w owns fixed chunk set
// {w+4j} (statically unrolled). No global loads inside the loop: bias1 lives
// in LDS and initializes the GEMM1 C operand.
__global__ __launch_bounds__(256, 2) void k_main(
    const u16* __restrict__ B1F, const u16* __restrict__ W2F,
    const float* __restrict__ mask, const float* __restrict__ depth,
    const float* __restrict__ cosx, const float* __restrict__ cosy,
    const float* __restrict__ bias1, const float* __restrict__ bias2,
    float* __restrict__ out)
{
  __shared__ __align__(16) u16 sbuf[3 * STAGE_U16];   // 76800 B
  __shared__ __align__(16) float lbias[1024];         // 4096 B (total 80896)
  float* stg = (float*)sbuf;                          // staging overlay

  const int tid = threadIdx.x;
  const int w = tid >> 6;
  const int lane = tid & 63;
  const int l31 = lane & 31;
  const int lhi = lane >> 5;
  const int r0 = blockIdx.x * 128;
  const int b = r0 >> 12;
  const int oy0 = (r0 >> 6) & 63;   // even

  // ---- stage: bias1 -> lbias; cosx[b] | cosy[b] 4 rows | mask,depth 4 rows ----
  {
    ((float4*)lbias)[tid] = ((const float4*)bias1)[tid];
    const float4* cx4 = (const float4*)(cosx + (size_t)b * 2048);
    ((float4*)stg)[tid]       = cx4[tid];
    ((float4*)stg)[tid + 256] = cx4[tid + 256];
    if (tid < 64)
      stg[2048 + tid] = cosy[((size_t)b * 16 + (tid >> 2)) * 128 + 2 * oy0 + (tid & 3)];
    if (tid < 128) {
      ((float4*)(stg + 2112))[tid] = ((const float4*)(mask  + ((size_t)b * 128 + 2 * oy0) * 128))[tid];
      ((float4*)(stg + 2624))[tid] = ((const float4*)(depth + ((size_t)b * 128 + 2 * oy0) * 128))[tid];
    }
  }
  __syncthreads();

  // ---- build this lane's 9 GEMM1 B-op frags directly in registers ----
  bf16x8 bfr[9];
  {
    const int r = w * 32 + l31;
    const int oyl = r >> 6, ox = r & 63;
    float m[4], dd[4];
#pragma unroll
    for (int j = 0; j < 4; ++j) {
      int sy = j >> 1, sx = j & 1;
      float mv = stg[2112 + (2 * oyl + sy) * 128 + 2 * ox + sx];
      m[j] = mv;
      dd[j] = stg[2624 + (2 * oyl + sy) * 128 + 2 * ox + sx] * mv;
    }
#pragma unroll
    for (int ks = 0; ks < 9; ++ks) {
      const int k0 = ks * 16 + lhi * 8;
      unsigned dwords[4];
#pragma unroll
      for (int h = 0; h < 4; ++h) {
        float v[2];
#pragma unroll
        for (int p = 0; p < 2; ++p) {
          const int k = k0 + 2 * h + p;
          float vv;
          if (k < 64) {
            const int f = k >> 2, j = k & 3;
            vv = m[j] * stg[f * 128 + 2 * ox + (j & 1)];
          } else if (k < 128) {
            const int kk = k - 64, f = kk >> 2, j = kk & 3;
            vv = m[j] * stg[2048 + f * 4 + 2 * oyl + (j >> 1)];
          } else if (k < 132) {
            vv = m[k - 128];
          } else if (k < 136) {
            vv = dd[k - 132];
          } else {
            vv = 0.f;
          }
          v[p] = vv;
        }
        dwords[h] = pk2(v[0], v[1]);
      }
      uint4 u; u.x = dwords[0]; u.y = dwords[1]; u.z = dwords[2]; u.w = dwords[3];
      bfr[ks] = __builtin_bit_cast(bf16x8, u);
    }
  }
  __syncthreads();   // all stg reads done before DMA overwrites sbuf

  f32x16 acc2[8];
#pragma unroll
  for (int c = 0; c < 8; ++c)
#pragma unroll
    for (int i = 0; i < 16; ++i) acc2[c][i] = 0.f;

  // per-wave fixed prefetch chunks: af c in {w+4j, c<9}; wf c in {wf0+4j}
  const int naf = (w == 0) ? 3 : 2;
  const int wf0 = 9 + ((w + 3) & 3);
  const u16* b1base = B1F + (size_t)b * 32 * 4608 + lane * 8;  // +4608/ch
  const u16* w2base = W2F + lane * 8;                          // +8192/ch

  auto prefetch = [&](const u16* asrc, const u16* wsrc, u16* dst) {
#pragma unroll
    for (int j = 0; j < 3; ++j)
      if (j < naf) gl_lds16(asrc + (w + 4 * j) * 512, dst + (w + 4 * j) * 512);
#pragma unroll
    for (int j = 0; j < 4; ++j) {
      const int c = wf0 + 4 * j;
      gl_lds16(wsrc + (c - 9) * 512, dst + c * 512);
    }
  };

  prefetch(b1base, w2base, sbuf);
  prefetch(b1base + 4608, w2base + 8192, sbuf + STAGE_U16);
  __syncthreads();   // vmcnt(0): stages 0,1 resident

  for (int ch = 0; ch < 32; ++ch) {
    const int st = ch % 3;
    if (ch + 2 < 32)
      prefetch(b1base + (size_t)(ch + 2) * 4608, w2base + (size_t)(ch + 2) * 8192,
               sbuf + ((ch + 2) % 3) * STAGE_U16);

    const u16* afb = sbuf + st * STAGE_U16;
    const u16* wfb = afb + 4608;
    const int n0 = ch * 32;

    // GEMM1: C[hidden 32][rows 32], C initialized with bias1 (from LDS)
    f32x16 acc1;
#pragma unroll
    for (int q = 0; q < 4; ++q) {
      f32x4 bi = *(const f32x4*)&lbias[n0 + 8 * q + 4 * lhi];
#pragma unroll
      for (int i = 0; i < 4; ++i) acc1[4 * q + i] = bi[i];
    }
#pragma unroll
    for (int ks = 0; ks < 9; ++ks) {
      bf16x8 af = *(const bf16x8*)(afb + ks * 512 + lane * 8);   // ds_read_b128
      acc1 = __builtin_amdgcn_mfma_f32_32x32x16_bf16(af, bfr[ks], acc1, 0, 0, 0);
    }

    // SiLU + fast pack to bf16 pairs
    unsigned d[8];
#pragma unroll
    for (int q = 0; q < 4; ++q) {
      d[2 * q]     = pk2f(silu(acc1[4 * q + 0]), silu(acc1[4 * q + 1]));
      d[2 * q + 1] = pk2f(silu(acc1[4 * q + 2]), silu(acc1[4 * q + 3]));
    }
    // C-layout -> A-op layout: exchange with lane^32 + half-select
    unsigned y0 = (unsigned)__shfl_xor((int)(lhi ? d[0] : d[2]), 32);
    unsigned y1 = (unsigned)__shfl_xor((int)(lhi ? d[1] : d[3]), 32);
    unsigned y2 = (unsigned)__shfl_xor((int)(lhi ? d[4] : d[6]), 32);
    unsigned y3 = (unsigned)__shfl_xor((int)(lhi ? d[5] : d[7]), 32);
    uint4 fa, fb;
    fa.x = lhi ? y0 : d[0];  fa.y = lhi ? y1 : d[1];
    fa.z = lhi ? d[2] : y0;  fa.w = lhi ? d[3] : y1;
    fb.x = lhi ? y2 : d[4];  fb.y = lhi ? y3 : d[5];
    fb.z = lhi ? d[6] : y2;  fb.w = lhi ? d[7] : y3;
    bf16x8 fragA = __builtin_bit_cast(bf16x8, fa);   // k = ch*32 + 0..15
    bf16x8 fragB = __builtin_bit_cast(bf16x8, fb);   // k = ch*32 + 16..31

    // GEMM2: acc2[ct] += S[rows][k16] * W2[n2][k16]
#pragma unroll
    for (int ct = 0; ct < 8; ++ct) {
      bf16x8 wf = *(const bf16x8*)(wfb + ct * 512 + lane * 8);
      acc2[ct] = __builtin_amdgcn_mfma_f32_32x32x16_bf16(fragA, wf, acc2[ct], 0, 0, 0);
    }
#pragma unroll
    for (int ct = 0; ct < 8; ++ct) {
      bf16x8 wf = *(const bf16x8*)(wfb + 4096 + ct * 512 + lane * 8);
      acc2[ct] = __builtin_amdgcn_mfma_f32_32x32x16_bf16(fragB, wf, acc2[ct], 0, 0, 0);
    }

    __syncthreads();   // drains this iter's DMA issue (one compute-phase old)
  }

  // ---- epilogue: out[b][n2][oy][ox] = acc2 + bias2, float4 along ox ----
#pragma unroll
  for (int ct = 0; ct < 8; ++ct) {
    const int n2 = ct * 32 + l31;
    const float b2 = bias2[n2];
    float* ob = out + ((size_t)b * 256 + n2) * 4096;
#pragma unroll
    for (int q = 0; q < 4; ++q) {
      const int rl = w * 32 + 8 * q + 4 * lhi;   // rows rl..rl+3 consecutive
      const int oy = oy0 + (rl >> 6);
      const int ox = rl & 63;
      f32x4 v;
      v[0] = acc2[ct][4 * q + 0] + b2;
      v[1] = acc2[ct][4 * q + 1] + b2;
      v[2] = acc2[ct][4 * q + 2] + b2;
      v[3] = acc2[ct][4 * q + 3] + b2;
      *(f32x4*)(ob + oy * 64 + ox) = v;
    }
  }
}

// ------------------------------- launcher ----------------------------------

extern "C" void kernel_launch(void* const* d_in, const int* in_sizes, int n_in,
                              void* d_out, int out_size, void* d_ws, size_t ws_size,
                              hipStream_t stream) {
  const float* pos     = (const float*)d_in[0];
  const float* gestalt = (const float*)d_in[1];
  const float* mask    = (const float*)d_in[2];
  const float* depth   = (const float*)d_in[3];
  const float* w1      = (const float*)d_in[4];
  const float* bias1   = (const float*)d_in[5];
  const float* w2      = (const float*)d_in[6];
  const float* bias2   = (const float*)d_in[7];
  float* out = (float*)d_out;

  // workspace: cosx 128KB | cosy 128KB | B1F 4.5MB | W2F 512KB = 5,505,024 B
  const size_t NEED = 131072u + 131072u + 4718592u + 524288u;
  if (ws_size < NEED) {
    fprintf(stderr, "[kernel] ws_size=%zu < needed %zu — skipping launches\n",
            ws_size, NEED);
    return;
  }
  char* ws = (char*)d_ws;
  float* cosx = (float*)(ws);
  float* cosy = (float*)(ws + 131072);
  u16*   B1F  = (u16*)(ws + 262144);
  u16*   W2F  = (u16*)(ws + 262144 + 4718592);

  k_pre<<<1408, 256, 0, stream>>>(pos, gestalt, w1, w2, cosx, cosy, B1F, W2F);
  k_main<<<512, 256, 0, stream>>>(B1F, W2F, mask, depth, cosx, cosy, bias1, bias2, out);
}

// Round 6
// 161.970 us; speedup vs baseline: 2.0471x; 1.0207x over previous
//
#include <hip/hip_runtime.h>
#include <cstdio>

// ---------------------------------------------------------------------------
// MemoryEfficientRGBDecoderStem — algebraic reduction + fused bf16 MFMA.
//   GEMM1 K collapses 1156 -> 137 (pad 144): gestalt spatially constant
//   (per-batch Wg), cos embeddings separable in h/w, bias1 folded into the
//   k=136 column (input-side frag carries 1.0 there).
//   R6: 2-stage LDS pipeline (vmcnt(0) barrier drain makes depth>1 useless),
//   51.2 KB LDS -> 3 blocks/CU; no bias LDS traffic.
// ---------------------------------------------------------------------------

#define NFREQ 16
#define BB 16
#define G 256
#define KIN 1156
#define K1 144
#define STAGE_U16 12800   // 25600 B per stage: af 9216 B + wf 16384 B

typedef unsigned short u16;
using bf16x8 = __bf16 __attribute__((ext_vector_type(8)));
using f32x16 = float __attribute__((ext_vector_type(16)));
using f32x4  = float __attribute__((ext_vector_type(4)));

__device__ __forceinline__ u16 f2bf(float f) {          // RNE (for weights)
  unsigned u = __float_as_uint(f);
  u += 0x7fffu + ((u >> 16) & 1u);
  return (u16)(u >> 16);
}
__device__ __forceinline__ unsigned pk2(float a, float b) {  // RNE pair
  return (unsigned)f2bf(a) | ((unsigned)f2bf(b) << 16);
}
// fast pair pack, round-half-up: 2x v_add + v_perm_b32
__device__ __forceinline__ unsigned pk2f(float a, float b) {
  unsigned ua = __float_as_uint(a) + 0x8000u;
  unsigned ub = __float_as_uint(b) + 0x8000u;
  return __builtin_amdgcn_perm(ub, ua, 0x07060302u);  // {ub.hi16, ua.hi16}
}
// fast silu: v_mul + v_exp_f32 + v_add + v_rcp_f32 + v_mul
__device__ __forceinline__ float silu(float h) {
  float e = __builtin_amdgcn_exp2f(h * -1.44269504088896f);
  return h * __builtin_amdgcn_rcpf(1.f + e);
}
// async global->LDS DMA: per-lane g addr, wave-uniform LDS base; lane i -> l + 16*i
__device__ __forceinline__ void gl_lds16(const u16* g, u16* l) {
  __builtin_amdgcn_global_load_lds(
      (const __attribute__((address_space(1))) void*)g,
      (__attribute__((address_space(3))) void*)l, 16, 0, 0);
}

// --------------------------- fused prologue --------------------------------
// blocks [0,1024): B1F build | [1024,1152): W2F pack | [1152,1408): cos tables
__global__ void k_pre(const float* __restrict__ pos,
                      const float* __restrict__ gestalt,
                      const float* __restrict__ w1,
                      const float* __restrict__ w2,
                      const float* __restrict__ bias1,
                      float* __restrict__ cosx, float* __restrict__ cosy,
                      u16* __restrict__ B1F, u16* __restrict__ W2F) {
  const int bid = blockIdx.x;
  const int t = threadIdx.x;

  if (bid < 1024) {
    // ---- B1F: per-batch reduced W1, frag-contiguous bf16, uint4 stores ----
    __shared__ float w1row[KIN];
    __shared__ float gestT[G * BB];   // transposed [c][bb]
    __shared__ float psum[256];
    __shared__ float wg[64];
    const int n = bid;
    const float b1v = bias1[n];       // folded into k=136 column
    for (int i = t; i < KIN; i += 256) w1row[i] = w1[(size_t)n * KIN + i];
    for (int i = t; i < BB * G; i += 256) {
      int bb = i >> 8, c = i & 255;
      gestT[c * BB + bb] = gestalt[i];
    }
    __syncthreads();
    {
      // Wg[bb][j] = sum_c gestalt[bb][c]*w1[n][4c+j]; t = q*64 + j*16 + bb
      int bb = t & 15, j = (t >> 4) & 3, q = t >> 6;
      float acc = 0.f;
#pragma unroll 8
      for (int c = q * 64; c < q * 64 + 64; ++c)
        acc += gestT[c * BB + bb] * w1row[4 * c + j];
      psum[t] = acc;
    }
    __syncthreads();
    if (t < 64) {
      int bb = t >> 2, j = t & 3;
      wg[t] = psum[j * 16 + bb] + psum[64 + j * 16 + bb] +
              psum[128 + j * 16 + bb] + psum[192 + j * 16 + bb];
    }
    __syncthreads();
    const int ch = n >> 5, l31n = n & 31;
    // 288 chunks of 8 consecutive k; one uint4 store each
    for (int c = t; c < BB * (K1 / 8); c += 256) {
      int bb = c / 18, kc = c - bb * 18;
      int k0 = kc * 8;
      float v[8];
#pragma unroll
      for (int i = 0; i < 8; ++i) {
        int k = k0 + i;
        float vv;
        if (k < 64)       vv = w1row[1024 + 8 * (k >> 2) + (k & 3)];
        else if (k < 128) { int kk = k - 64; vv = w1row[1024 + 8 * (kk >> 2) + 4 + (kk & 3)]; }
        else if (k < 132) vv = wg[bb * 4 + (k - 128)];
        else if (k < 136) vv = w1row[1152 + (k - 132)];
        else if (k == 136) vv = b1v;   // bias column
        else              vv = 0.f;
        v[i] = vv;
      }
      uint4 u;
      u.x = pk2(v[0], v[1]); u.y = pk2(v[2], v[3]);
      u.z = pk2(v[4], v[5]); u.w = pk2(v[6], v[7]);
      size_t idx0 = ((((size_t)bb * 32 + ch) * 9 + (kc >> 1)) * 64 +
                     (kc & 1) * 32 + l31n) * 8;
      *(uint4*)(B1F + idx0) = u;
    }
  } else if (bid < 1152) {
    // ---- W2F: frag-contiguous bf16; 8 u16 per thread, uint4 store ----
    int e8 = (bid - 1024) * 256 + t;    // 0..32767
    int lane = e8 & 63;
    int ct   = (e8 >> 6) & 7;
    int kc   = e8 >> 9;
    int n2 = ct * 32 + (lane & 31);
    int k2 = kc * 16 + (lane >> 5) * 8;
    const float* src = w2 + (size_t)n2 * 1024 + k2;
    uint4 u;
    u.x = pk2(src[0], src[1]); u.y = pk2(src[2], src[3]);
    u.z = pk2(src[4], src[5]); u.w = pk2(src[6], src[7]);
    *(uint4*)(W2F + (size_t)e8 * 8) = u;
  } else {
    // ---- cos tables (exact fp32 op-order of reference) ----
    int idx = (bid - 1152) * 256 + t;   // 0..65535
    int table = idx >> 15;
    int rem = idx & 32767;
    int b = rem >> 11;
    int f = (rem >> 7) & 15;
    int c = rem & 127;
    float p0 = pos[b * 4 + 0];
    float p1 = pos[b * 4 + 1];
    float p3 = pos[b * 4 + 3];
    float x = fminf(fmaxf(p0, -1.f), 1.f);
    float y = fminf(fmaxf(p1, -1.f), 1.f);
    float stdv = 0.1f / fminf(fmaxf(p3, 0.0078125f), 0.5f);  // min_std = 1/128
    const float half_pi = 1.57079632679489661923f;
    float g = ((float)c / 127.0f) * 2.0f - 1.0f;
    float ng = (table == 0) ? ((g - x) * stdv) * half_pi     // std_x = std (W/H=1)
                            : ((g - y) * stdv) * half_pi;
    float freq = (float)(1 << f);
    float val = cosf(ng * freq);
    if (table == 0) cosx[(b * NFREQ + f) * 128 + c] = val;
    else            cosy[(b * NFREQ + f) * 128 + c] = val;
  }
}

// ------------------------------ main kernel --------------------------------
// 512 blocks x 256 thr (4 waves). Wave w owns rows [w*32,w*32+32), all 1024
// hidden, all 256 n2. Operand streams (af, wf) flow through a 2-stage LDS
// pipeline (51.2 KB -> 3 blocks/CU) filled by async global_load_lds; wave w
// owns fixed DMA chunk set. bias1 rides the GEMM1 MFMA via the k=136 column.
__global__ __launch_bounds__(256, 2) void k_main(
    const u16* __restrict__ B1F, const u16* __restrict__ W2F,
    const float* __restrict__ mask, const float* __restrict__ depth,
    const float* __restrict__ cosx, const float* __restrict__ cosy,
    const float* __restrict__ bias2, float* __restrict__ out)
{
  __shared__ __align__(16) u16 sbuf[2 * STAGE_U16];   // 51200 B total LDS
  float* stg = (float*)sbuf;                          // staging overlay

  const int tid = threadIdx.x;
  const int w = tid >> 6;
  const int lane = tid & 63;
  const int l31 = lane & 31;
  const int lhi = lane >> 5;
  const int r0 = blockIdx.x * 128;
  const int b = r0 >> 12;
  const int oy0 = (r0 >> 6) & 63;   // even

  // ---- stage tables: cosx[b] 2048f | cosy[b] 4 h-rows 64f | mask,depth 4 rows ----
  {
    const float4* cx4 = (const float4*)(cosx + (size_t)b * 2048);
    ((float4*)stg)[tid]       = cx4[tid];
    ((float4*)stg)[tid + 256] = cx4[tid + 256];
    if (tid < 64)
      stg[2048 + tid] = cosy[((size_t)b * 16 + (tid >> 2)) * 128 + 2 * oy0 + (tid & 3)];
    if (tid < 128) {
      ((float4*)(stg + 2112))[tid] = ((const float4*)(mask  + ((size_t)b * 128 + 2 * oy0) * 128))[tid];
      ((float4*)(stg + 2624))[tid] = ((const float4*)(depth + ((size_t)b * 128 + 2 * oy0) * 128))[tid];
    }
  }
  __syncthreads();

  // ---- build this lane's 9 GEMM1 B-op frags directly in registers ----
  // k=136 carries 1.0 so B1F's bias column lands as +bias1[n].
  bf16x8 bfr[9];
  {
    const int r = w * 32 + l31;
    const int oyl = r >> 6, ox = r & 63;
    float m[4], dd[4];
#pragma unroll
    for (int j = 0; j < 4; ++j) {
      int sy = j >> 1, sx = j & 1;
      float mv = stg[2112 + (2 * oyl + sy) * 128 + 2 * ox + sx];
      m[j] = mv;
      dd[j] = stg[2624 + (2 * oyl + sy) * 128 + 2 * ox + sx] * mv;
    }
#pragma unroll
    for (int ks = 0; ks < 9; ++ks) {
      const int k0 = ks * 16 + lhi * 8;
      unsigned dwords[4];
#pragma unroll
      for (int h = 0; h < 4; ++h) {
        float v[2];
#pragma unroll
        for (int p = 0; p < 2; ++p) {
          const int k = k0 + 2 * h + p;
          float vv;
          if (k < 64) {
            const int f = k >> 2, j = k & 3;
            vv = m[j] * stg[f * 128 + 2 * ox + (j & 1)];
          } else if (k < 128) {
            const int kk = k - 64, f = kk >> 2, j = kk & 3;
            vv = m[j] * stg[2048 + f * 4 + 2 * oyl + (j >> 1)];
          } else if (k < 132) {
            vv = m[k - 128];
          } else if (k < 136) {
            vv = dd[k - 132];
          } else if (k == 136) {
            vv = 1.0f;               // bias passthrough
          } else {
            vv = 0.f;
          }
          v[p] = vv;
        }
        dwords[h] = pk2(v[0], v[1]);
      }
      uint4 u; u.x = dwords[0]; u.y = dwords[1]; u.z = dwords[2]; u.w = dwords[3];
      bfr[ks] = __builtin_bit_cast(bf16x8, u);
    }
  }
  __syncthreads();   // all stg reads done before DMA overwrites sbuf

  f32x16 acc2[8];
#pragma unroll
  for (int c = 0; c < 8; ++c)
#pragma unroll
    for (int i = 0; i < 16; ++i) acc2[c][i] = 0.f;

  // per-wave fixed prefetch chunks: af c in {w+4j, c<9}; wf c in {wf0+4j}
  const int naf = (w == 0) ? 3 : 2;
  const int wf0 = 9 + ((w + 3) & 3);
  const u16* b1base = B1F + (size_t)b * 32 * 4608 + lane * 8;  // +4608/ch
  const u16* w2base = W2F + lane * 8;                          // +8192/ch

  auto prefetch = [&](const u16* asrc, const u16* wsrc, u16* dst) {
#pragma unroll
    for (int j = 0; j < 3; ++j)
      if (j < naf) gl_lds16(asrc + (w + 4 * j) * 512, dst + (w + 4 * j) * 512);
#pragma unroll
    for (int j = 0; j < 4; ++j) {
      const int c = wf0 + 4 * j;
      gl_lds16(wsrc + (c - 9) * 512, dst + c * 512);
    }
  };

  prefetch(b1base, w2base, sbuf);   // stage 0 = ch 0
  __syncthreads();                  // vmcnt(0): stage 0 resident

  for (int ch = 0; ch < 32; ++ch) {
    const int st = ch & 1;
    if (ch + 1 < 32)                // fill the other stage for ch+1
      prefetch(b1base + (size_t)(ch + 1) * 4608, w2base + (size_t)(ch + 1) * 8192,
               sbuf + (st ^ 1) * STAGE_U16);

    const u16* afb = sbuf + st * STAGE_U16;
    const u16* wfb = afb + 4608;

    // GEMM1: C[hidden 32][rows 32] (+bias via k=136 column)
    f32x16 acc1;
#pragma unroll
    for (int i = 0; i < 16; ++i) acc1[i] = 0.f;
#pragma unroll
    for (int ks = 0; ks < 9; ++ks) {
      bf16x8 af = *(const bf16x8*)(afb + ks * 512 + lane * 8);   // ds_read_b128
      acc1 = __builtin_amdgcn_mfma_f32_32x32x16_bf16(af, bfr[ks], acc1, 0, 0, 0);
    }

    // SiLU + fast pack to bf16 pairs
    unsigned d[8];
#pragma unroll
    for (int q = 0; q < 4; ++q) {
      d[2 * q]     = pk2f(silu(acc1[4 * q + 0]), silu(acc1[4 * q + 1]));
      d[2 * q + 1] = pk2f(silu(acc1[4 * q + 2]), silu(acc1[4 * q + 3]));
    }
    // C-layout -> A-op layout: exchange with lane^32 + half-select
    unsigned y0 = (unsigned)__shfl_xor((int)(lhi ? d[0] : d[2]), 32);
    unsigned y1 = (unsigned)__shfl_xor((int)(lhi ? d[1] : d[3]), 32);
    unsigned y2 = (unsigned)__shfl_xor((int)(lhi ? d[4] : d[6]), 32);
    unsigned y3 = (unsigned)__shfl_xor((int)(lhi ? d[5] : d[7]), 32);
    uint4 fa, fb;
    fa.x = lhi ? y0 : d[0];  fa.y = lhi ? y1 : d[1];
    fa.z = lhi ? d[2] : y0;  fa.w = lhi ? d[3] : y1;
    fb.x = lhi ? y2 : d[4];  fb.y = lhi ? y3 : d[5];
    fb.z = lhi ? d[6] : y2;  fb.w = lhi ? d[7] : y3;
    bf16x8 fragA = __builtin_bit_cast(bf16x8, fa);   // k = ch*32 + 0..15
    bf16x8 fragB = __builtin_bit_cast(bf16x8, fb);   // k = ch*32 + 16..31

    // GEMM2: acc2[ct] += S[rows][k16] * W2[n2][k16]
#pragma unroll
    for (int ct = 0; ct < 8; ++ct) {
      bf16x8 wf = *(const bf16x8*)(wfb + ct * 512 + lane * 8);
      acc2[ct] = __builtin_amdgcn_mfma_f32_32x32x16_bf16(fragA, wf, acc2[ct], 0, 0, 0);
    }
#pragma unroll
    for (int ct = 0; ct < 8; ++ct) {
      bf16x8 wf = *(const bf16x8*)(wfb + 4096 + ct * 512 + lane * 8);
      acc2[ct] = __builtin_amdgcn_mfma_f32_32x32x16_bf16(fragB, wf, acc2[ct], 0, 0, 0);
    }

    __syncthreads();   // drains next-stage DMA (issued one compute-phase ago)
  }

  // ---- epilogue: out[b][n2][oy][ox] = acc2 + bias2, float4 along ox ----
#pragma unroll
  for (int ct = 0; ct < 8; ++ct) {
    const int n2 = ct * 32 + l31;
    const float b2 = bias2[n2];
    float* ob = out + ((size_t)b * 256 + n2) * 4096;
#pragma unroll
    for (int q = 0; q < 4; ++q) {
      const int rl = w * 32 + 8 * q + 4 * lhi;   // rows rl..rl+3 consecutive
      const int oy = oy0 + (rl >> 6);
      const int ox = rl & 63;
      f32x4 v;
      v[0] = acc2[ct][4 * q + 0] + b2;
      v[1] = acc2[ct][4 * q + 1] + b2;
      v[2] = acc2[ct][4 * q + 2] + b2;
      v[3] = acc2[ct][4 * q + 3] + b2;
      *(f32x4*)(ob + oy * 64 + ox) = v;
    }
  }
}

// ------------------------------- launcher ----------------------------------

extern "C" void kernel_launch(void* const* d_in, const int* in_sizes, int n_in,
                              void* d_out, int out_size, void* d_ws, size_t ws_size,
                              hipStream_t stream) {
  const float* pos     = (const float*)d_in[0];
  const float* gestalt = (const float*)d_in[1];
  const float* mask    = (const float*)d_in[2];
  const float* depth   = (const float*)d_in[3];
  const float* w1      = (const float*)d_in[4];
  const float* bias1   = (const float*)d_in[5];
  const float* w2      = (const float*)d_in[6];
  const float* bias2   = (const float*)d_in[7];
  float* out = (float*)d_out;

  // workspace: cosx 128KB | cosy 128KB | B1F 4.5MB | W2F 512KB = 5,505,024 B
  const size_t NEED = 131072u + 131072u + 4718592u + 524288u;
  if (ws_size < NEED) {
    fprintf(stderr, "[kernel] ws_size=%zu < needed %zu — skipping launches\n",
            ws_size, NEED);
    return;
  }
  char* ws = (char*)d_ws;
  float* cosx = (float*)(ws);
  float* cosy = (float*)(ws + 131072);
  u16*   B1F  = (u16*)(ws + 262144);
  u16*   W2F  = (u16*)(ws + 262144 + 4718592);

  k_pre<<<1408, 256, 0, stream>>>(pos, gestalt, w1, w2, bias1, cosx, cosy, B1F, W2F);
  k_main<<<512, 256, 0, stream>>>(B1F, W2F, mask, depth, cosx, cosy, bias2, out);
}